// Round 7
// baseline (1003.814 us; speedup 1.0000x reference)
//
#include <hip/hip_runtime.h>
#include <math.h>

// ---------------------------------------------------------------------------
// Disentangler: 32 component-MLPs over sampled token rows + masked seg-pool.
// Round-7: true 8-phase K-loop (T3+T4): per K=64 tile, 4 quadrant phases per
// wave, each {ds_read new frags | stage 1 half-tile | barrier | lgkm(0) |
// setprio | 16 MFMA | barrier}; stage leads consumption by 5 phases; one
// vmcnt(2) gate per tile (never 0 in steady state). 256^2 tile, 8 waves,
// pre-swizzled bf16 operands (Ab, Wt1, Wt2, h), glds staging, T1 swizzle.
// ---------------------------------------------------------------------------

typedef __attribute__((ext_vector_type(8))) short bf16x8;
typedef __attribute__((ext_vector_type(4))) float f32x4;
typedef unsigned int u32;

constexpr int TT    = 16;
constexpr int TOKN  = 4096;
constexpr int DD    = 2048;
constexpr int HH    = 2048;
constexpr int CC    = 1024;
constexpr int LL    = 1000;
constexpr int NCOMP = 32;
constexpr int MP    = 1024;
constexpr int MT256 = MP / 256;   // 4 m-tiles
constexpr int NT1X  = HH / 256;   // 8 n-tiles (gemm1)
constexpr int NT2X  = CC / 256;   // 4 n-tiles (gemm2)
constexpr int NTILE = DD / 64;    // 32 K-tiles (same for both GEMMs)

__device__ __forceinline__ short f2bf(float f) {
  __bf16 h = (__bf16)f;
  return *reinterpret_cast<short*>(&h);
}
// Row swizzle (period 64): granule g of a 64-elem chunk lives at slot
// g ^ swz(row). Identical in Ab, Wt1, Wt2, h, and LDS tiles.
__device__ __forceinline__ int swz(int row) {
  return (row & 7) ^ ((row >> 3) & 7);
}
__device__ __forceinline__ int sw(int row, int gran) {   // short offset
  return (row << 6) + ((gran ^ swz(row)) << 3);
}
__device__ __forceinline__ void gl_lds16(const void* g, void* l) {
  __builtin_amdgcn_global_load_lds(
      (const __attribute__((address_space(1))) u32*)g,
      (__attribute__((address_space(3))) u32*)l, 16, 0, 0);
}

// --------------------------- dedup ----------------------------------------
__global__ void dedup_kernel(const int* __restrict__ ridx,
                             unsigned* __restrict__ bitmap,
                             float* __restrict__ keepf) {
  int comp = blockIdx.x;
  for (int l = threadIdx.x; l < MP; l += 256) {
    float kv = 0.0f;
    if (l < LL) {
      int r = ridx[comp * LL + l];
      unsigned bit = 1u << (r & 31);
      unsigned old = atomicOr(&bitmap[(comp << 10) + (r >> 5)], bit);
      kv = (old & bit) ? 0.0f : 1.0f;
    }
    keepf[(comp << 10) + l] = kv;
  }
}

// --------------------------- gather: x rows -> pre-swizzled bf16 -----------
__global__ __launch_bounds__(256) void gather_kernel(
    const float* __restrict__ x, const int* __restrict__ ridx,
    short* __restrict__ Ab) {
  int bid = blockIdx.x;
  int comp = bid >> 7, rgrp = bid & 127;
  int t = threadIdx.x;
  int tr = t >> 5, tn = t & 31;
  int m = rgrp * 8 + tr;
  int mi = m < LL ? m : LL - 1;
  int r = ridx[comp * LL + mi];
  int tokoff = comp >= 16 ? TOKN / 2 : 0;
  const float* src = x + ((size_t)(r >> 11) * TOKN + (r & 2047) + tokoff) * DD;
  short* drow = Ab + ((size_t)(comp * MP + m)) * DD;
  int s_m = swz(m);
#pragma unroll
  for (int i = 0; i < 8; ++i) {
    int gi = tn + 32 * i;
    float4 f0 = *reinterpret_cast<const float4*>(src + gi * 8);
    float4 f1 = *reinterpret_cast<const float4*>(src + gi * 8 + 4);
    bf16x8 pk;
    pk[0]=f2bf(f0.x); pk[1]=f2bf(f0.y); pk[2]=f2bf(f0.z); pk[3]=f2bf(f0.w);
    pk[4]=f2bf(f1.x); pk[5]=f2bf(f1.y); pk[6]=f2bf(f1.z); pk[7]=f2bf(f1.w);
    int c = gi >> 3, g = gi & 7;
    *reinterpret_cast<bf16x8*>(&drow[c * 64 + ((g ^ s_m) << 3)]) = pk;
  }
}

// --------------------------- transpose W -> pre-swizzled bf16 [n][k] -------
__global__ __launch_bounds__(256) void transW_kernel(
    const float* __restrict__ nsrc, const float* __restrict__ esrc,
    short* __restrict__ dst, int N, int NTt) {
  __shared__ float tile[64][65];
  int bid = blockIdx.x;
  int comp = bid / (32 * NTt);
  int rem = bid % (32 * NTt);
  int kt = rem / NTt, ntile = rem % NTt;
  int k0 = kt * 64, n0 = ntile * 64;
  const float* src = (comp < 16) ? nsrc + (size_t)comp * DD * N
                                 : esrc + (size_t)(comp - 16) * DD * N;
  int t = threadIdx.x;
  int kr = t >> 2, j0 = (t & 3) * 16;
  const float* sp = src + (size_t)(k0 + kr) * N + n0 + j0;
#pragma unroll
  for (int e = 0; e < 4; ++e) {
    float4 v = *reinterpret_cast<const float4*>(sp + 4 * e);
    tile[kr][j0 + 4*e]     = v.x;
    tile[kr][j0 + 4*e + 1] = v.y;
    tile[kr][j0 + 4*e + 2] = v.z;
    tile[kr][j0 + 4*e + 3] = v.w;
  }
  __syncthreads();
  int nr = t >> 2, i0 = (t & 3) * 16;
  int n = n0 + nr;
  int s_n = swz(n);
  short* drow = dst + ((size_t)comp * N + n) * DD;
  int chunk = k0 >> 6;
#pragma unroll
  for (int h = 0; h < 2; ++h) {
    int g = ((i0 >> 3) + h) & 7;
    bf16x8 pk;
#pragma unroll
    for (int e = 0; e < 8; ++e) pk[e] = f2bf(tile[i0 + h * 8 + e][nr]);
    *reinterpret_cast<bf16x8*>(&drow[chunk * 64 + ((g ^ s_n) << 3)]) = pk;
  }
}

// --------------------------- shared 8-phase K-loop -------------------------
// LDS layout (shorts): A[dbuf][half][8192] @0, B[dbuf][half][8192] @32768.
// Stage schedule (tile t): p0->A-h1(t+1), p1->B-h0(t+1), p2->B-h1(t+1),
// p3->A-h0(t+2); gate vmcnt(2) at p3. Ledger-verified write-after-read.
__device__ __forceinline__ void kloop256(
    const short* __restrict__ Ag, const short* __restrict__ Bg,
    short* sm, f32x4 (&acc)[8][4], int wr, int wc, int lr, int lg, int tid) {
  int f1 = 512 + tid;
  size_t so0 = (size_t)(tid >> 3) * DD + (tid & 7) * 8;
  size_t so1 = (size_t)(f1 >> 3) * DD + (f1 & 7) * 8;
  int lo0 = tid * 8, lo1 = f1 * 8;
  const size_t HS = (size_t)128 * DD;           // half row-block (shorts)

  auto stA = [&](int t, int d, int h) {
    const short* s = Ag + h * HS + (size_t)t * 64;
    short* l = sm + (d * 2 + h) * 8192;
    gl_lds16(s + so0, l + lo0);
    gl_lds16(s + so1, l + lo1);
  };
  auto stB = [&](int t, int d, int h) {
    const short* s = Bg + h * HS + (size_t)t * 64;
    short* l = sm + 32768 + (d * 2 + h) * 8192;
    gl_lds16(s + so0, l + lo0);
    gl_lds16(s + so1, l + lo1);
  };
  auto rdA = [&](int d, int ih, int kk, int i) -> bf16x8 {
    int row = ih * 64 + i * 16 + lr;
    return *reinterpret_cast<const bf16x8*>(&sm[(d * 2 + wr) * 8192 + sw(row, kk * 4 + lg)]);
  };
  auto rdB = [&](int d, int jh, int kk, int j) -> bf16x8 {
    int row = (wc & 1) * 64 + jh * 32 + j * 16 + lr;
    return *reinterpret_cast<const bf16x8*>(&sm[32768 + (d * 2 + (wc >> 1)) * 8192 + sw(row, kk * 4 + lg)]);
  };

  // prologue: tile 0 fully + A-h0 of tile 1; allow the newest 2 loads in flight
  stA(0, 0, 0); stA(0, 0, 1); stB(0, 0, 0); stB(0, 0, 1); stA(1, 1, 0);
  asm volatile("s_waitcnt vmcnt(2)" ::: "memory");
  __builtin_amdgcn_sched_barrier(0);
  __builtin_amdgcn_s_barrier();

  bf16x8 af[2][4], bj0[2][2], bj1[2][2];

#pragma unroll 1
  for (int t = 0; t < NTILE; ++t) {
    int d = t & 1, nd = d ^ 1;
    // ---- phase 0: read A-ih0 (8) + B-jh0 (4); MFMA quadrant (0,0)
#pragma unroll
    for (int kk = 0; kk < 2; ++kk) {
#pragma unroll
      for (int i = 0; i < 4; ++i) af[kk][i] = rdA(d, 0, kk, i);
#pragma unroll
      for (int j = 0; j < 2; ++j) bj0[kk][j] = rdB(d, 0, kk, j);
    }
    if (t < NTILE - 1) stA(t + 1, nd, 1);
    __builtin_amdgcn_s_barrier();
    asm volatile("s_waitcnt lgkmcnt(0)" ::: "memory");
    __builtin_amdgcn_sched_barrier(0);
    __builtin_amdgcn_s_setprio(1);
#pragma unroll
    for (int kk = 0; kk < 2; ++kk)
#pragma unroll
      for (int i = 0; i < 4; ++i)
#pragma unroll
        for (int j = 0; j < 2; ++j)
          acc[i][j] = __builtin_amdgcn_mfma_f32_16x16x32_bf16(af[kk][i], bj0[kk][j], acc[i][j], 0, 0, 0);
    __builtin_amdgcn_s_setprio(0);
    __builtin_amdgcn_s_barrier();
    // ---- phase 1: read B-jh1 (4); MFMA quadrant (0,1)
#pragma unroll
    for (int kk = 0; kk < 2; ++kk)
#pragma unroll
      for (int j = 0; j < 2; ++j) bj1[kk][j] = rdB(d, 1, kk, j);
    if (t < NTILE - 1) stB(t + 1, nd, 0);
    __builtin_amdgcn_s_barrier();
    asm volatile("s_waitcnt lgkmcnt(0)" ::: "memory");
    __builtin_amdgcn_sched_barrier(0);
    __builtin_amdgcn_s_setprio(1);
#pragma unroll
    for (int kk = 0; kk < 2; ++kk)
#pragma unroll
      for (int i = 0; i < 4; ++i)
#pragma unroll
        for (int j = 0; j < 2; ++j)
          acc[i][2 + j] = __builtin_amdgcn_mfma_f32_16x16x32_bf16(af[kk][i], bj1[kk][j], acc[i][2 + j], 0, 0, 0);
    __builtin_amdgcn_s_setprio(0);
    __builtin_amdgcn_s_barrier();
    // ---- phase 2: read A-ih1 (8); MFMA quadrant (1,1)
#pragma unroll
    for (int kk = 0; kk < 2; ++kk)
#pragma unroll
      for (int i = 0; i < 4; ++i) af[kk][i] = rdA(d, 1, kk, i);
    if (t < NTILE - 1) stB(t + 1, nd, 1);
    __builtin_amdgcn_s_barrier();
    asm volatile("s_waitcnt lgkmcnt(0)" ::: "memory");
    __builtin_amdgcn_sched_barrier(0);
    __builtin_amdgcn_s_setprio(1);
#pragma unroll
    for (int kk = 0; kk < 2; ++kk)
#pragma unroll
      for (int i = 0; i < 4; ++i)
#pragma unroll
        for (int j = 0; j < 2; ++j)
          acc[4 + i][2 + j] = __builtin_amdgcn_mfma_f32_16x16x32_bf16(af[kk][i], bj1[kk][j], acc[4 + i][2 + j], 0, 0, 0);
    __builtin_amdgcn_s_setprio(0);
    __builtin_amdgcn_s_barrier();
    // ---- phase 3: no reads; stage A-h0(t+2); vmcnt gate; MFMA quadrant (1,0)
    if (t < NTILE - 2) stA(t + 2, d, 0);
    if (t < NTILE - 2) {
      asm volatile("s_waitcnt vmcnt(2)" ::: "memory");     // tile t+1 landed
    } else if (t == NTILE - 2) {
      asm volatile("s_waitcnt vmcnt(0)" ::: "memory");     // final drain
    }
    __builtin_amdgcn_sched_barrier(0);
    __builtin_amdgcn_s_barrier();
    __builtin_amdgcn_s_setprio(1);
#pragma unroll
    for (int kk = 0; kk < 2; ++kk)
#pragma unroll
      for (int i = 0; i < 4; ++i)
#pragma unroll
        for (int j = 0; j < 2; ++j)
          acc[4 + i][j] = __builtin_amdgcn_mfma_f32_16x16x32_bf16(af[kk][i], bj0[kk][j], acc[4 + i][j], 0, 0, 0);
    __builtin_amdgcn_s_setprio(0);
    __builtin_amdgcn_s_barrier();
  }
}

// --------------------------- GEMM1: h = gelu(x_sel @ W1 + b1) --------------
__global__ __launch_bounds__(512, 2) void gemm1_kernel(
    const float* __restrict__ nb1, const float* __restrict__ eb1,
    const short* __restrict__ Ab, const short* __restrict__ Wt1,
    short* __restrict__ hbuf) {
  __shared__ short smem[65536];   // 128 KB

  constexpr int NWG = NCOMP * MT256 * NT1X;   // 1024
  constexpr int CPX = NWG / 8;
  int b0 = blockIdx.x;
  int lb = (b0 & 7) * CPX + (b0 >> 3);        // XCD-chunked (T1), bijective
  int comp = lb / (MT256 * NT1X);
  int rem  = lb % (MT256 * NT1X);
  int mt = rem / NT1X, nt = rem % NT1X;
  const float* b1 = (comp < 16) ? nb1 + (size_t)comp * HH
                                : eb1 + (size_t)(comp - 16) * HH;

  int tid = threadIdx.x, lane = tid & 63, wid = tid >> 6;
  int wr = wid >> 2, wc = wid & 3;
  int lr = lane & 15, lg = lane >> 4;

  const short* Ag = Ab  + ((size_t)(comp * MP + mt * 256)) * DD;
  const short* Bg = Wt1 + ((size_t)(comp * HH + nt * 256)) * DD;

  f32x4 acc[8][4] = {};
  kloop256(Ag, Bg, smem, acc, wr, wc, lr, lg, tid);

  // epilogue: +b1, exact gelu; two 128-row phases bounce through LDS, then
  // coalesced PRE-SWIZZLED bf16 h store (so gemm2 can global_load_lds it)
  short* Cs = smem;                            // stride 264 shorts
  const float* b1p = b1 + nt * 256;
#pragma unroll 1
  for (int p = 0; p < 2; ++p) {
    if (wr == p) {
#pragma unroll
      for (int i = 0; i < 8; ++i)
#pragma unroll
        for (int j = 0; j < 4; ++j) {
          int nl = wc * 64 + j * 16 + lr;
          float bias = b1p[nl];
#pragma unroll
          for (int rr = 0; rr < 4; ++rr) {
            int r = i * 16 + lg * 4 + rr;      // 0..127 within phase
            float v = acc[i][j][rr] + bias;
            float ge = 0.5f * v * (1.0f + erff(v * 0.70710678118654752f));
            Cs[r * 264 + nl] = f2bf(ge);
          }
        }
    }
    __syncthreads();
    short* hrow = hbuf + ((size_t)(comp * MP + mt * 256 + p * 128)) * HH;
#pragma unroll
    for (int q = 0; q < 8; ++q) {
      int f = q * 512 + tid;
      int r = f >> 5, g8 = f & 31;             // 32 8-short granules per row
      bf16x8 v = *reinterpret_cast<const bf16x8*>(&Cs[r * 264 + g8 * 8]);
      int dst = (nt * 4 + (g8 >> 3)) * 64 + (((g8 & 7) ^ swz(r)) << 3);
      *reinterpret_cast<bf16x8*>(&hrow[(size_t)r * HH + dst]) = v;
    }
    __syncthreads();
  }
}

// --------------------------- GEMM2: o = h @ W2 + b2, masked seg-reduce -----
__global__ __launch_bounds__(512, 2) void gemm2_kernel(
    const short* __restrict__ hbuf, const int* __restrict__ ridx,
    const float* __restrict__ nb2, const float* __restrict__ eb2,
    const short* __restrict__ Wt2,
    const float* __restrict__ keepf, float* __restrict__ partial) {
  __shared__ short smem[65536];

  constexpr int NWG = NCOMP * MT256 * NT2X;   // 512
  constexpr int CPX = NWG / 8;
  int b0 = blockIdx.x;
  int lb = (b0 & 7) * CPX + (b0 >> 3);
  int comp = lb / (MT256 * NT2X);
  int rem  = lb % (MT256 * NT2X);
  int mt = rem / NT2X, nt = rem % NT2X;
  const float* b2 = (comp < 16) ? nb2 + (size_t)comp * CC
                                : eb2 + (size_t)(comp - 16) * CC;

  int tid = threadIdx.x, lane = tid & 63, wid = tid >> 6;
  int wr = wid >> 2, wc = wid & 3;
  int lr = lane & 15, lg = lane >> 4;

  const short* Ag = hbuf + ((size_t)(comp * MP + mt * 256)) * HH;
  const short* Bg = Wt2  + ((size_t)(comp * CC + nt * 256)) * HH;

  f32x4 acc[8][4] = {};
  kloop256(Ag, Bg, smem, acc, wr, wc, lr, lg, tid);

  // epilogue: (+b2) * keep, seg-reduce 256 rows by timestamp (LDS reused)
  float* part = (float*)smem;                  // 16*256 floats = 16 KB
  int*   tarr = (int*)((char*)smem + 16384);   // 256 ints
  float* karr = (float*)((char*)smem + 17408); // 256 floats
  if (tid < 256) {
    int mglob = mt * 256 + tid;
    int mi = mglob < LL ? mglob : LL - 1;
    int r2 = ridx[comp * LL + mi];
    tarr[tid] = r2 >> 11;
    karr[tid] = keepf[(comp << 10) + mglob];   // 0 for padded/duplicate rows
  }
  for (int e = tid; e < TT * 256; e += 512) part[e] = 0.0f;
  __syncthreads();
  const float* b2p = b2 + nt * 256;
#pragma unroll
  for (int i = 0; i < 8; ++i)
#pragma unroll
    for (int j = 0; j < 4; ++j) {
      int nl = wc * 64 + j * 16 + lr;
      float bias = b2p[nl];
#pragma unroll
      for (int rr = 0; rr < 4; ++rr) {
        int ml = wr * 128 + i * 16 + lg * 4 + rr;
        float v = (acc[i][j][rr] + bias) * karr[ml];
        atomicAdd(&part[tarr[ml] * 256 + nl], v);
      }
    }
  __syncthreads();
  float* pout = partial + ((size_t)(comp * MT256 + mt)) * TT * CC + nt * 256;
  for (int e = tid; e < TT * 256; e += 512) {
    int t2 = e >> 8, c = e & 255;
    pout[(size_t)t2 * CC + c] = part[e];
  }
}

// --------------------------- final reduce over m-tiles ---------------------
__global__ void reduce_kernel(const float* __restrict__ partial,
                              float* __restrict__ out) {
  int idx = blockIdx.x * 256 + threadIdx.x;     // = t*32768 + comp*1024 + c
  int c    = idx & (CC - 1);
  int comp = (idx >> 10) & (NCOMP - 1);
  int t    = idx >> 15;
  float s = 0.0f;
#pragma unroll
  for (int mt = 0; mt < MT256; ++mt)
    s += partial[(((size_t)(comp * MT256 + mt)) * TT + t) * CC + c];
  out[idx] = s * (1.0f / 4096.0f);
}

// ---------------------------------------------------------------------------
extern "C" void kernel_launch(void* const* d_in, const int* in_sizes, int n_in,
                              void* d_out, int out_size, void* d_ws, size_t ws_size,
                              hipStream_t stream) {
  const float* x    = (const float*)d_in[0];
  const int*   ridx = (const int*)d_in[3];
  const float* nW1  = (const float*)d_in[4];
  const float* nb1  = (const float*)d_in[5];
  const float* nW2  = (const float*)d_in[6];
  const float* nb2  = (const float*)d_in[7];
  const float* eW1  = (const float*)d_in[8];
  const float* eb1  = (const float*)d_in[9];
  const float* eW2  = (const float*)d_in[10];
  const float* eb2  = (const float*)d_in[11];
  float* out = (float*)d_out;

  // ws: [h 134MB][bitmap][keep][partial 8MB][Ab/Wt2 134MB][Wt1 268MB] ~546MB
  const size_t H_B   = (size_t)NCOMP * MP * HH * 2;
  const size_t BMP_B = (size_t)NCOMP * 1024 * 4;
  const size_t KP_B  = (size_t)NCOMP * 1024 * 4;
  const size_t PRT_B = (size_t)NCOMP * MT256 * TT * CC * 4;
  const size_t base  = H_B + BMP_B + KP_B + PRT_B;
  const size_t AB_B  = (size_t)NCOMP * MP * DD * 2;

  char* ws = (char*)d_ws;
  short* hbuf      = (short*)ws;
  unsigned* bitmap = (unsigned*)(ws + H_B);
  float* keepf     = (float*)(ws + H_B + BMP_B);
  float* partial   = (float*)(ws + H_B + BMP_B + KP_B);
  short* Ab        = (short*)(ws + base);            // reused as Wt2 later
  short* Wt1       = (short*)(ws + base + AB_B);

  hipMemsetAsync(bitmap, 0, BMP_B, stream);
  dedup_kernel<<<NCOMP, 256, 0, stream>>>(ridx, bitmap, keepf);
  gather_kernel<<<NCOMP * 128, 256, 0, stream>>>(x, ridx, Ab);
  transW_kernel<<<NCOMP * 32 * 32, 256, 0, stream>>>(nW1, eW1, Wt1, HH, 32);
  gemm1_kernel<<<NCOMP * MT256 * NT1X, 512, 0, stream>>>(nb1, eb1, Ab, Wt1, hbuf);
  transW_kernel<<<NCOMP * 32 * 16, 256, 0, stream>>>(nW2, eW2, Ab, CC, 16);
  gemm2_kernel<<<NCOMP * MT256 * NT2X, 512, 0, stream>>>(hbuf, ridx, nb2, eb2, Ab, keepf, partial);
  reduce_kernel<<<out_size / 256, 256, 0, stream>>>(partial, out);
}

// Round 8
// 937.582 us; speedup vs baseline: 1.0706x; 1.0706x over previous
//
#include <hip/hip_runtime.h>
#include <math.h>

// ---------------------------------------------------------------------------
// Disentangler: 32 component-MLPs over sampled token rows + masked seg-pool.
// Round-8: W-transpose folded INTO the GEMMs (B: coalesced fp32 row loads ->
// reg transpose+cvt -> swizzled ds_write; A: pure global_load_lds of
// pre-swizzled bf16). Minimal 1-barrier counted-vmcnt K-loop; compiler
// schedules frag-reads/MFMA interleave (no lgkm/sched fences inside).
// transW prep kernels eliminated (~180 us, 1.2 GB traffic).
// ---------------------------------------------------------------------------

typedef __attribute__((ext_vector_type(8))) short bf16x8;
typedef __attribute__((ext_vector_type(4))) short s16x4;
typedef __attribute__((ext_vector_type(4))) float f32x4;
typedef unsigned int u32;

constexpr int TT    = 16;
constexpr int TOKN  = 4096;
constexpr int DD    = 2048;
constexpr int HH    = 2048;
constexpr int CC    = 1024;
constexpr int LL    = 1000;
constexpr int NCOMP = 32;
constexpr int MP    = 1024;
constexpr int BM = 128, BN = 128;
constexpr int MT  = MP / BM;      // 8
constexpr int NT1 = HH / BN;      // 16
constexpr int NT2 = CC / BN;      // 8
constexpr int NT  = 2048 / 64;    // 32 K-tiles (K = DD = HH = 2048 both GEMMs)

__device__ __forceinline__ short f2bf(float f) {
  __bf16 h = (__bf16)f;
  return *reinterpret_cast<short*>(&h);
}
// Row swizzle (period 64): data-granule g of a 64-elem chunk lives at slot
// g ^ swz(row). Identical layout in Ab, h, and the LDS tiles.
__device__ __forceinline__ int swz(int row) {
  return (row & 7) ^ ((row >> 3) & 7);
}
__device__ __forceinline__ int sw(int row, int gran) {   // short offset
  return (row << 6) + ((gran ^ swz(row)) << 3);
}
__device__ __forceinline__ void gl_lds16(const void* g, void* l) {
  __builtin_amdgcn_global_load_lds(
      (const __attribute__((address_space(1))) u32*)g,
      (__attribute__((address_space(3))) u32*)l, 16, 0, 0);
}

// --------------------------- dedup ----------------------------------------
__global__ void dedup_kernel(const int* __restrict__ ridx,
                             unsigned* __restrict__ bitmap,
                             float* __restrict__ keepf) {
  int comp = blockIdx.x;
  for (int l = threadIdx.x; l < MP; l += 256) {
    float kv = 0.0f;
    if (l < LL) {
      int r = ridx[comp * LL + l];
      unsigned bit = 1u << (r & 31);
      unsigned old = atomicOr(&bitmap[(comp << 10) + (r >> 5)], bit);
      kv = (old & bit) ? 0.0f : 1.0f;
    }
    keepf[(comp << 10) + l] = kv;
  }
}

// --------------------------- gather: x rows -> pre-swizzled bf16 -----------
__global__ __launch_bounds__(256) void gather_kernel(
    const float* __restrict__ x, const int* __restrict__ ridx,
    short* __restrict__ Ab) {
  int bid = blockIdx.x;
  int comp = bid >> 7, rgrp = bid & 127;
  int t = threadIdx.x;
  int tr = t >> 5, tn = t & 31;
  int m = rgrp * 8 + tr;
  int mi = m < LL ? m : LL - 1;
  int r = ridx[comp * LL + mi];
  int tokoff = comp >= 16 ? TOKN / 2 : 0;
  const float* src = x + ((size_t)(r >> 11) * TOKN + (r & 2047) + tokoff) * DD;
  short* drow = Ab + ((size_t)(comp * MP + m)) * DD;
  int s_m = swz(m);
#pragma unroll
  for (int i = 0; i < 8; ++i) {
    int gi = tn + 32 * i;
    float4 f0 = *reinterpret_cast<const float4*>(src + gi * 8);
    float4 f1 = *reinterpret_cast<const float4*>(src + gi * 8 + 4);
    bf16x8 pk;
    pk[0]=f2bf(f0.x); pk[1]=f2bf(f0.y); pk[2]=f2bf(f0.z); pk[3]=f2bf(f0.w);
    pk[4]=f2bf(f1.x); pk[5]=f2bf(f1.y); pk[6]=f2bf(f1.z); pk[7]=f2bf(f1.w);
    int c = gi >> 3, g = gi & 7;
    *reinterpret_cast<bf16x8*>(&drow[c * 64 + ((g ^ s_m) << 3)]) = pk;
  }
}

// --------------------------- shared K-loop ---------------------------------
// LDS (shorts): Abuf[2][8192] @0, Bbuf[2][8192] @16384.
// Per tile t: B(t) already in Bbuf[t&1]; this body cvt+writes B(t+1) from a
// reg set (loaded last body), loads B(t+2) regs, computes, then issues
// A-glds(t+2) after the barrier. vmcnt(12) gate: in-flight at entry is
// [A(t)(4 glds), Breg(t+1)(8), A(t+1)(4 glds)] -> drains A(t). One barrier.
template<int LDW>
__device__ __forceinline__ void kloop128(
    const short* __restrict__ aBase,   // bf16 pre-swizzled rows, stride 2048
    const float* __restrict__ wBase,   // fp32 W [k][LDW] at col offset nt*BN
    short* sm, f32x4 (&acc)[4][4],
    int wm, int wn, int lr, int lg, int tid) {
  const short* aSrc[4]; int ldsOff[4];
#pragma unroll
  for (int q = 0; q < 4; ++q) {
    int f = q * 256 + tid, ar = f >> 3, sl = f & 7;
    aSrc[q] = aBase + (size_t)ar * 2048 + sl * 8;
    ldsOff[q] = f * 8;
  }
  int tn = tid & 31, tkb = tid >> 5, bn0 = tn * 4;
  const float* wCol = wBase + bn0;

  float4 brA[8], brB[8];

  auto aglds = [&](int t, int buf) {
    short* l = sm + buf * 8192;
#pragma unroll
    for (int q = 0; q < 4; ++q) gl_lds16(aSrc[q] + t * 64, l + ldsOff[q]);
  };
  auto bload = [&](int t, float4* br) {
    const float* bb = wCol + (size_t)(t * 64 + tkb * 8) * LDW;
#pragma unroll
    for (int i = 0; i < 8; ++i)
      br[i] = *reinterpret_cast<const float4*>(bb + (size_t)i * LDW);
  };
  auto bwrite = [&](const float4* br, int nb) {
    short* Bs = sm + 16384 + nb * 8192;
#pragma unroll
    for (int j = 0; j < 4; ++j) {
      bf16x8 pk;
#pragma unroll
      for (int i = 0; i < 8; ++i) pk[i] = f2bf((&br[i].x)[j]);
      *reinterpret_cast<bf16x8*>(&Bs[sw(bn0 + j, tkb)]) = pk;
    }
  };
  auto compute = [&](int d) {
    const short* A = sm + d * 8192;
    const short* B = sm + 16384 + d * 8192;
#pragma unroll
    for (int kk = 0; kk < 2; ++kk) {
      bf16x8 af[4], bfr[4];
#pragma unroll
      for (int i = 0; i < 4; ++i)
        af[i] = *reinterpret_cast<const bf16x8*>(&A[sw(wm + i * 16 + lr, kk * 4 + lg)]);
#pragma unroll
      for (int j = 0; j < 4; ++j)
        bfr[j] = *reinterpret_cast<const bf16x8*>(&B[sw(wn + j * 16 + lr, kk * 4 + lg)]);
      __builtin_amdgcn_s_setprio(1);
#pragma unroll
      for (int i = 0; i < 4; ++i)
#pragma unroll
        for (int j = 0; j < 4; ++j)
          acc[i][j] = __builtin_amdgcn_mfma_f32_16x16x32_bf16(af[i], bfr[j], acc[i][j], 0, 0, 0);
      __builtin_amdgcn_s_setprio(0);
    }
  };

  // prologue: A(0),A(1) glds; B(0)->regs->Bbuf[0]; B(1)->regs
  aglds(0, 0);
  bload(0, brA);
  aglds(1, 1);
  bwrite(brA, 0);                 // compiler inserts the vmcnt for brA
  bload(1, brB);
  asm volatile("s_waitcnt lgkmcnt(0)" ::: "memory");
  __builtin_amdgcn_s_barrier();

#pragma unroll 1
  for (int tp = 0; tp < NT / 2; ++tp) {
    int t0 = tp * 2, t1 = t0 + 1;
    // ---- even body (tile t0, buffers d=0): write B(t0+1), load B(t0+2)
    asm volatile("s_waitcnt vmcnt(12)" ::: "memory");   // A(t0) landed
    __builtin_amdgcn_sched_barrier(0);
    bwrite(brB, 1);                                     // B(t0+1) -> Bbuf[1]
    if (t0 + 2 < NT) bload(t0 + 2, brA);
    compute(0);
    asm volatile("s_waitcnt lgkmcnt(0)" ::: "memory");  // drain B ds_writes
    __builtin_amdgcn_s_barrier();
    if (t0 + 2 < NT) aglds(t0 + 2, 0);
    // ---- odd body (tile t1, buffers d=1): write B(t1+1), load B(t1+2)
    if (t1 + 1 < NT) {
      asm volatile("s_waitcnt vmcnt(12)" ::: "memory"); // A(t1) landed
    } else {
      asm volatile("s_waitcnt vmcnt(0)" ::: "memory");  // final drain
    }
    __builtin_amdgcn_sched_barrier(0);
    if (t1 + 1 < NT) bwrite(brA, 0);                    // B(t1+1) -> Bbuf[0]
    if (t1 + 2 < NT) bload(t1 + 2, brB);
    compute(1);
    asm volatile("s_waitcnt lgkmcnt(0)" ::: "memory");
    __builtin_amdgcn_s_barrier();
    if (t1 + 2 < NT) aglds(t1 + 2, 1);
  }
}

// --------------------------- GEMM1: h = gelu(x_sel @ W1 + b1) --------------
__global__ __launch_bounds__(256, 2) void gemm1_kernel(
    const float* __restrict__ nW1, const float* __restrict__ nb1,
    const float* __restrict__ eW1, const float* __restrict__ eb1,
    const short* __restrict__ Ab, short* __restrict__ hbuf) {
  __shared__ short smem[32768];   // 64 KB

  constexpr int NWG = NCOMP * MT * NT1;   // 4096
  constexpr int CPX = NWG / 8;
  int b0 = blockIdx.x;
  int lb = (b0 & 7) * CPX + (b0 >> 3);    // XCD-chunked (T1), bijective
  int comp = lb / (MT * NT1);
  int rem  = lb % (MT * NT1);
  int mt = rem / NT1, nt = rem % NT1;
  bool isEdge = comp >= 16;
  int k16 = isEdge ? comp - 16 : comp;
  const float* W1 = (isEdge ? eW1 : nW1) + (size_t)k16 * DD * HH;
  const float* b1 = (isEdge ? eb1 : nb1) + (size_t)k16 * HH;

  int tid = threadIdx.x, lane = tid & 63, wid = tid >> 6;
  int wm = (wid >> 1) << 6, wn = (wid & 1) << 6;
  int lr = lane & 15, lg = lane >> 4;

  f32x4 acc[4][4] = {};
  kloop128<HH>(Ab + ((size_t)(comp * MP + mt * BM)) * DD,
               W1 + nt * BN, smem, acc, wm, wn, lr, lg, tid);

  // epilogue: +b1, exact gelu -> Cs (stride 132), then coalesced
  // PRE-SWIZZLED bf16 h store (so gemm2 can global_load_lds it)
  __builtin_amdgcn_s_barrier();
  short* Cs = smem;                        // 128*132 = 16896 shorts
  const float* b1p = b1 + nt * BN;
#pragma unroll
  for (int i = 0; i < 4; ++i)
#pragma unroll
    for (int j = 0; j < 4; ++j) {
      int nl = wn + j * 16 + lr;
      float bias = b1p[nl];
#pragma unroll
      for (int rr = 0; rr < 4; ++rr) {
        int ml = wm + i * 16 + lg * 4 + rr;
        float v = acc[i][j][rr] + bias;
        float ge = 0.5f * v * (1.0f + erff(v * 0.70710678118654752f));
        Cs[ml * 132 + nl] = f2bf(ge);
      }
    }
  __syncthreads();
  short* hrow = hbuf + ((size_t)(comp * MP + mt * BM)) * HH;
#pragma unroll
  for (int q = 0; q < 16; ++q) {
    int gl = q * 256 + tid;
    int r = gl >> 5, gg = gl & 31;         // 32 4-short granules per row
    s16x4 v = *reinterpret_cast<const s16x4*>(&Cs[r * 132 + gg * 4]);
    int dst = (nt * 2 + (gg >> 4)) * 64 + ((((gg >> 1) & 7) ^ swz(r)) << 3) + (gg & 1) * 4;
    *reinterpret_cast<s16x4*>(&hrow[(size_t)r * HH + dst]) = v;
  }
}

// --------------------------- GEMM2: o = h @ W2 + b2, masked seg-reduce -----
__global__ __launch_bounds__(256, 2) void gemm2_kernel(
    const short* __restrict__ hbuf, const int* __restrict__ ridx,
    const float* __restrict__ nW2, const float* __restrict__ nb2,
    const float* __restrict__ eW2, const float* __restrict__ eb2,
    const float* __restrict__ keepf, float* __restrict__ partial) {
  __shared__ short smem[32768];

  constexpr int NWG = NCOMP * MT * NT2;   // 2048
  constexpr int CPX = NWG / 8;
  int b0 = blockIdx.x;
  int lb = (b0 & 7) * CPX + (b0 >> 3);
  int comp = lb / (MT * NT2);
  int rem  = lb % (MT * NT2);
  int mt = rem / NT2, nt = rem % NT2;
  bool isEdge = comp >= 16;
  int k16 = isEdge ? comp - 16 : comp;
  const float* W2 = (isEdge ? eW2 : nW2) + (size_t)k16 * HH * CC;
  const float* b2 = (isEdge ? eb2 : nb2) + (size_t)k16 * CC;

  int tid = threadIdx.x, lane = tid & 63, wid = tid >> 6;
  int wm = (wid >> 1) << 6, wn = (wid & 1) << 6;
  int lr = lane & 15, lg = lane >> 4;

  f32x4 acc[4][4] = {};
  kloop128<CC>(hbuf + ((size_t)(comp * MP + mt * BM)) * HH,
               W2 + nt * BN, smem, acc, wm, wn, lr, lg, tid);

  // epilogue: (+b2) * keep, seg-reduce by timestamp (LDS reused)
  __builtin_amdgcn_s_barrier();
  float* part = (float*)smem;              // 2048 floats (8 KB)
  int*   tarr = (int*)(smem + 4096);       // byte 8192, 128 ints
  float* karr = (float*)(smem + 4352);     // byte 8704, 128 floats
  if (tid < BM) {
    int mglob = mt * BM + tid;
    int mi = mglob < LL ? mglob : LL - 1;
    int r2 = ridx[comp * LL + mi];
    tarr[tid] = r2 >> 11;
    karr[tid] = keepf[(comp << 10) + mglob];
  }
  for (int e = tid; e < TT * BN; e += 256) part[e] = 0.0f;
  __syncthreads();
  const float* b2p = b2 + nt * BN;
#pragma unroll
  for (int i = 0; i < 4; ++i)
#pragma unroll
    for (int j = 0; j < 4; ++j) {
      int nl = wn + j * 16 + lr;
      float bias = b2p[nl];
#pragma unroll
      for (int rr = 0; rr < 4; ++rr) {
        int ml = wm + i * 16 + lg * 4 + rr;
        float v = (acc[i][j][rr] + bias) * karr[ml];
        atomicAdd(&part[tarr[ml] * BN + nl], v);
      }
    }
  __syncthreads();
  float* pout = partial + ((size_t)(comp * MT + mt)) * TT * CC + nt * BN;
  for (int e = tid; e < TT * BN; e += 256) {
    int t2 = e >> 7, c = e & 127;
    pout[(size_t)t2 * CC + c] = part[e];
  }
}

// --------------------------- final reduce over m-tiles ---------------------
__global__ void reduce_kernel(const float* __restrict__ partial,
                              float* __restrict__ out) {
  int idx = blockIdx.x * 256 + threadIdx.x;
  int c    = idx & (CC - 1);
  int comp = (idx >> 10) & (NCOMP - 1);
  int t    = idx >> 15;
  float s = 0.0f;
#pragma unroll
  for (int mt = 0; mt < MT; ++mt)
    s += partial[(((size_t)(comp * MT + mt)) * TT + t) * CC + c];
  out[idx] = s * (1.0f / 4096.0f);
}

// ---------------------------------------------------------------------------
extern "C" void kernel_launch(void* const* d_in, const int* in_sizes, int n_in,
                              void* d_out, int out_size, void* d_ws, size_t ws_size,
                              hipStream_t stream) {
  const float* x    = (const float*)d_in[0];
  const int*   ridx = (const int*)d_in[3];
  const float* nW1  = (const float*)d_in[4];
  const float* nb1  = (const float*)d_in[5];
  const float* nW2  = (const float*)d_in[6];
  const float* nb2  = (const float*)d_in[7];
  const float* eW1  = (const float*)d_in[8];
  const float* eb1  = (const float*)d_in[9];
  const float* eW2  = (const float*)d_in[10];
  const float* eb2  = (const float*)d_in[11];
  float* out = (float*)d_out;

  // ws: [h 134MB][bitmap][keep][partial 16.8MB][Ab 134MB]  ~285 MB
  const size_t H_B   = (size_t)NCOMP * MP * HH * 2;
  const size_t BMP_B = (size_t)NCOMP * 1024 * 4;
  const size_t KP_B  = (size_t)NCOMP * 1024 * 4;
  const size_t PRT_B = (size_t)NCOMP * MT * TT * CC * 4;
  const size_t base  = H_B + BMP_B + KP_B + PRT_B;

  char* ws = (char*)d_ws;
  short* hbuf      = (short*)ws;
  unsigned* bitmap = (unsigned*)(ws + H_B);
  float* keepf     = (float*)(ws + H_B + BMP_B);
  float* partial   = (float*)(ws + H_B + BMP_B + KP_B);
  short* Ab        = (short*)(ws + base);

  hipMemsetAsync(bitmap, 0, BMP_B, stream);
  dedup_kernel<<<NCOMP, 256, 0, stream>>>(ridx, bitmap, keepf);
  gather_kernel<<<NCOMP * 128, 256, 0, stream>>>(x, ridx, Ab);
  gemm1_kernel<<<NCOMP * MT * NT1, 256, 0, stream>>>(nW1, nb1, eW1, eb1, Ab, hbuf);
  gemm2_kernel<<<NCOMP * MT * NT2, 256, 0, stream>>>(hbuf, ridx, nW2, nb2, eW2, eb2, keepf, partial);
  reduce_kernel<<<out_size / 256, 256, 0, stream>>>(partial, out);
}

// Round 9
// 805.224 us; speedup vs baseline: 1.2466x; 1.1644x over previous
//
#include <hip/hip_runtime.h>
#include <math.h>

// ---------------------------------------------------------------------------
// Disentangler: 32 component-MLPs over sampled token rows + masked seg-pool.
// Round-9: fused W-transpose GEMMs with 256x128 block / 4 waves of 128x64
// (1.33x FLOP per LDS byte vs 64x64), A double-buffered via global_load_lds
// (pre-swizzled bf16), B single-buffered (fp32 row loads -> reg cvt ->
// swizzled ds_write), 80 KB LDS -> 2 blocks/CU, counted-vmcnt pipeline.
// ---------------------------------------------------------------------------

typedef __attribute__((ext_vector_type(8))) short bf16x8;
typedef __attribute__((ext_vector_type(4))) short s16x4;
typedef __attribute__((ext_vector_type(4))) float f32x4;
typedef unsigned int u32;

constexpr int TT    = 16;
constexpr int TOKN  = 4096;
constexpr int DD    = 2048;
constexpr int HH    = 2048;
constexpr int CC    = 1024;
constexpr int LL    = 1000;
constexpr int NCOMP = 32;
constexpr int MP    = 1024;
constexpr int BMX = 256, BNX = 128;
constexpr int MTX  = MP / BMX;    // 4 m-tiles
constexpr int NT1 = HH / BNX;     // 16 n-tiles (gemm1)
constexpr int NT2 = CC / BNX;     // 8  n-tiles (gemm2)
constexpr int NT  = 2048 / 64;    // 32 K-tiles (K = 2048 both GEMMs)

__device__ __forceinline__ short f2bf(float f) {
  __bf16 h = (__bf16)f;
  return *reinterpret_cast<short*>(&h);
}
// Row swizzle (period 64): data-granule g of a 64-elem chunk lives at slot
// g ^ swz(row). Identical layout in Ab, h, and the LDS tiles.
__device__ __forceinline__ int swz(int row) {
  return (row & 7) ^ ((row >> 3) & 7);
}
__device__ __forceinline__ int sw(int row, int gran) {   // short offset
  return (row << 6) + ((gran ^ swz(row)) << 3);
}
__device__ __forceinline__ void gl_lds16(const void* g, void* l) {
  __builtin_amdgcn_global_load_lds(
      (const __attribute__((address_space(1))) u32*)g,
      (__attribute__((address_space(3))) u32*)l, 16, 0, 0);
}

// --------------------------- dedup ----------------------------------------
__global__ void dedup_kernel(const int* __restrict__ ridx,
                             unsigned* __restrict__ bitmap,
                             float* __restrict__ keepf) {
  int comp = blockIdx.x;
  for (int l = threadIdx.x; l < MP; l += 256) {
    float kv = 0.0f;
    if (l < LL) {
      int r = ridx[comp * LL + l];
      unsigned bit = 1u << (r & 31);
      unsigned old = atomicOr(&bitmap[(comp << 10) + (r >> 5)], bit);
      kv = (old & bit) ? 0.0f : 1.0f;
    }
    keepf[(comp << 10) + l] = kv;
  }
}

// --------------------------- gather: x rows -> pre-swizzled bf16 -----------
__global__ __launch_bounds__(256) void gather_kernel(
    const float* __restrict__ x, const int* __restrict__ ridx,
    short* __restrict__ Ab) {
  int bid = blockIdx.x;
  int comp = bid >> 7, rgrp = bid & 127;
  int t = threadIdx.x;
  int tr = t >> 5, tn = t & 31;
  int m = rgrp * 8 + tr;
  int mi = m < LL ? m : LL - 1;
  int r = ridx[comp * LL + mi];
  int tokoff = comp >= 16 ? TOKN / 2 : 0;
  const float* src = x + ((size_t)(r >> 11) * TOKN + (r & 2047) + tokoff) * DD;
  short* drow = Ab + ((size_t)(comp * MP + m)) * DD;
  int s_m = swz(m);
#pragma unroll
  for (int i = 0; i < 8; ++i) {
    int gi = tn + 32 * i;
    float4 f0 = *reinterpret_cast<const float4*>(src + gi * 8);
    float4 f1 = *reinterpret_cast<const float4*>(src + gi * 8 + 4);
    bf16x8 pk;
    pk[0]=f2bf(f0.x); pk[1]=f2bf(f0.y); pk[2]=f2bf(f0.z); pk[3]=f2bf(f0.w);
    pk[4]=f2bf(f1.x); pk[5]=f2bf(f1.y); pk[6]=f2bf(f1.z); pk[7]=f2bf(f1.w);
    int c = gi >> 3, g = gi & 7;
    *reinterpret_cast<bf16x8*>(&drow[c * 64 + ((g ^ s_m) << 3)]) = pk;
  }
}

// --------------------------- shared K-loop ---------------------------------
// LDS (shorts): Abuf[2][16384] @0 (256 rows x 64k), Bbuf[8192] @32768.
// Steady-state tile t: gate vmcnt(16) (A(t) oldest beyond bB(t+1)+A(t+1)),
// compute, barrier, bwrite(t+1), bload(t+2), aglds(t+2), lgkm(0), barrier.
template<int LDW>
__device__ __forceinline__ void kloop(
    const short* __restrict__ aBase,   // bf16 pre-swizzled rows, stride 2048
    const float* __restrict__ wBase,   // fp32 W [k][LDW] at col offset nt*BNX
    short* sm, f32x4 (&acc)[8][4],
    int wm, int wn, int lr, int lg, int tid) {
  const short* aSrc0 = aBase + (size_t)(tid >> 3) * 2048 + (tid & 7) * 8;
  int ldsA0 = tid * 8;
  int tn = tid & 31, tkb = tid >> 5, bn0 = tn * 4;
  const float* wCol = wBase + bn0;

  float4 brB[8];

  auto aglds = [&](int t, int buf) {
    short* l = sm + buf * 16384;
#pragma unroll
    for (int q = 0; q < 8; ++q)
      gl_lds16(aSrc0 + (size_t)q * 65536 + t * 64, l + ldsA0 + q * 2048);
  };
  auto bload = [&](int t) {
    const float* bb = wCol + (size_t)(t * 64 + tkb * 8) * LDW;
#pragma unroll
    for (int i = 0; i < 8; ++i)
      brB[i] = *reinterpret_cast<const float4*>(bb + (size_t)i * LDW);
  };
  auto bwrite = [&]() {
    short* Bs = sm + 32768;
#pragma unroll
    for (int j = 0; j < 4; ++j) {
      bf16x8 pk;
#pragma unroll
      for (int i = 0; i < 8; ++i) pk[i] = f2bf((&brB[i].x)[j]);
      *reinterpret_cast<bf16x8*>(&Bs[sw(bn0 + j, tkb)]) = pk;
    }
  };
  auto compute = [&](int d) {
    const short* A = sm + d * 16384;
    const short* B = sm + 32768;
#pragma unroll
    for (int kk = 0; kk < 2; ++kk) {
      bf16x8 af[8], bfr[4];
#pragma unroll
      for (int i = 0; i < 8; ++i)
        af[i] = *reinterpret_cast<const bf16x8*>(&A[sw(wm + i * 16 + lr, kk * 4 + lg)]);
#pragma unroll
      for (int j = 0; j < 4; ++j)
        bfr[j] = *reinterpret_cast<const bf16x8*>(&B[sw(wn + j * 16 + lr, kk * 4 + lg)]);
      __builtin_amdgcn_s_setprio(1);
#pragma unroll
      for (int i = 0; i < 8; ++i)
#pragma unroll
        for (int j = 0; j < 4; ++j)
          acc[i][j] = __builtin_amdgcn_mfma_f32_16x16x32_bf16(af[i], bfr[j], acc[i][j], 0, 0, 0);
      __builtin_amdgcn_s_setprio(0);
    }
  };

  // prologue: bB(0) regs; A(0) glds; write B(0) (compiler waits bB(0) only,
  // vmcnt(8) -> A(0) stays in flight); bB(1); A(1) glds.
  bload(0);
  aglds(0, 0);
  bwrite();
  bload(1);
  aglds(1, 1);
  asm volatile("s_waitcnt lgkmcnt(0)" ::: "memory");
  __builtin_amdgcn_s_barrier();

#pragma unroll 1
  for (int t = 0; t < NT; ++t) {
    if (t < NT - 1) {
      asm volatile("s_waitcnt vmcnt(16)" ::: "memory");  // A(t) landed
    } else {
      asm volatile("s_waitcnt vmcnt(0)" ::: "memory");
    }
    __builtin_amdgcn_sched_barrier(0);
    compute(t & 1);
    __builtin_amdgcn_s_barrier();          // all waves done reading A(t), B(t)
    if (t + 1 < NT) {
      bwrite();                            // B(t+1) -> Bbuf (vmcnt(8) auto)
      if (t + 2 < NT) {
        bload(t + 2);                      // issued BEFORE aglds (ordering!)
        aglds(t + 2, t & 1);
      }
      asm volatile("s_waitcnt lgkmcnt(0)" ::: "memory");
      __builtin_amdgcn_s_barrier();
    }
  }
}

// --------------------------- GEMM1: h = gelu(x_sel @ W1 + b1) --------------
__global__ __launch_bounds__(256, 2) void gemm1_kernel(
    const float* __restrict__ nW1, const float* __restrict__ nb1,
    const float* __restrict__ eW1, const float* __restrict__ eb1,
    const short* __restrict__ Ab, short* __restrict__ hbuf) {
  __shared__ short smem[40960];   // 80 KB

  constexpr int NWG = NCOMP * MTX * NT1;   // 2048
  constexpr int CPX = NWG / 8;
  int b0 = blockIdx.x;
  int lb = (b0 & 7) * CPX + (b0 >> 3);     // XCD-chunked (T1), bijective
  int comp = lb / (MTX * NT1);
  int rem  = lb % (MTX * NT1);
  int mt = rem / NT1, nt = rem % NT1;
  bool isEdge = comp >= 16;
  int k16 = isEdge ? comp - 16 : comp;
  const float* W1 = (isEdge ? eW1 : nW1) + (size_t)k16 * DD * HH;
  const float* b1 = (isEdge ? eb1 : nb1) + (size_t)k16 * HH;

  int tid = threadIdx.x, lane = tid & 63, wid = tid >> 6;
  int wm = (wid >> 1) << 7, wn = (wid & 1) << 6;   // 2x2 waves of 128x64
  int lr = lane & 15, lg = lane >> 4;

  f32x4 acc[8][4] = {};
  kloop<HH>(Ab + ((size_t)(comp * MP + mt * BMX)) * DD,
            W1 + nt * BNX, smem, acc, wm, wn, lr, lg, tid);

  // epilogue: +b1, exact gelu -> Cs (stride 132), then coalesced
  // PRE-SWIZZLED bf16 h store (so gemm2 can global_load_lds it)
  __builtin_amdgcn_s_barrier();
  short* Cs = smem;                        // 256*132 = 33792 shorts
  const float* b1p = b1 + nt * BNX;
#pragma unroll
  for (int i = 0; i < 8; ++i)
#pragma unroll
    for (int j = 0; j < 4; ++j) {
      int nl = wn + j * 16 + lr;
      float bias = b1p[nl];
#pragma unroll
      for (int rr = 0; rr < 4; ++rr) {
        int ml = wm + i * 16 + lg * 4 + rr;
        float v = acc[i][j][rr] + bias;
        float ge = 0.5f * v * (1.0f + erff(v * 0.70710678118654752f));
        Cs[ml * 132 + nl] = f2bf(ge);
      }
    }
  __syncthreads();
  short* hrow = hbuf + ((size_t)(comp * MP + mt * BMX)) * HH;
#pragma unroll
  for (int q = 0; q < 32; ++q) {
    int gl = q * 256 + tid;
    int r = gl >> 5, gg = gl & 31;         // 32 4-short granules per row
    s16x4 v = *reinterpret_cast<const s16x4*>(&Cs[r * 132 + gg * 4]);
    int dst = (nt * 2 + (gg >> 4)) * 64 + ((((gg >> 1) & 7) ^ swz(r)) << 3) + (gg & 1) * 4;
    *reinterpret_cast<s16x4*>(&hrow[(size_t)r * HH + dst]) = v;
  }
}

// --------------------------- GEMM2: o = h @ W2 + b2, masked seg-reduce -----
__global__ __launch_bounds__(256, 2) void gemm2_kernel(
    const short* __restrict__ hbuf, const int* __restrict__ ridx,
    const float* __restrict__ nW2, const float* __restrict__ nb2,
    const float* __restrict__ eW2, const float* __restrict__ eb2,
    const float* __restrict__ keepf, float* __restrict__ partial) {
  __shared__ short smem[40960];

  constexpr int NWG = NCOMP * MTX * NT2;   // 1024
  constexpr int CPX = NWG / 8;
  int b0 = blockIdx.x;
  int lb = (b0 & 7) * CPX + (b0 >> 3);
  int comp = lb / (MTX * NT2);
  int rem  = lb % (MTX * NT2);
  int mt = rem / NT2, nt = rem % NT2;
  bool isEdge = comp >= 16;
  int k16 = isEdge ? comp - 16 : comp;
  const float* W2 = (isEdge ? eW2 : nW2) + (size_t)k16 * HH * CC;
  const float* b2 = (isEdge ? eb2 : nb2) + (size_t)k16 * CC;

  int tid = threadIdx.x, lane = tid & 63, wid = tid >> 6;
  int wm = (wid >> 1) << 7, wn = (wid & 1) << 6;
  int lr = lane & 15, lg = lane >> 4;

  f32x4 acc[8][4] = {};
  kloop<CC>(hbuf + ((size_t)(comp * MP + mt * BMX)) * HH,
            W2 + nt * BNX, smem, acc, wm, wn, lr, lg, tid);

  // epilogue: (+b2) * keep, seg-reduce 256 rows by timestamp (LDS reused)
  __builtin_amdgcn_s_barrier();
  float* part = (float*)smem;                   // 16*128 floats = 8 KB
  int*   tarr = (int*)((char*)smem + 8192);     // 256 ints
  float* karr = (float*)((char*)smem + 9216);   // 256 floats
  if (tid < BMX) {
    int mglob = mt * BMX + tid;
    int mi = mglob < LL ? mglob : LL - 1;
    int r2 = ridx[comp * LL + mi];
    tarr[tid] = r2 >> 11;
    karr[tid] = keepf[(comp << 10) + mglob];    // 0 for padded/duplicate rows
  }
  for (int e = tid; e < TT * BNX; e += 256) part[e] = 0.0f;
  __syncthreads();
  const float* b2p = b2 + nt * BNX;
#pragma unroll
  for (int i = 0; i < 8; ++i)
#pragma unroll
    for (int j = 0; j < 4; ++j) {
      int nl = wn + j * 16 + lr;
      float bias = b2p[nl];
#pragma unroll
      for (int rr = 0; rr < 4; ++rr) {
        int ml = wm + i * 16 + lg * 4 + rr;
        float v = (acc[i][j][rr] + bias) * karr[ml];
        atomicAdd(&part[tarr[ml] * BNX + nl], v);
      }
    }
  __syncthreads();
  float* pout = partial + ((size_t)(comp * MTX + mt)) * TT * CC + nt * BNX;
  for (int e = tid; e < TT * BNX; e += 256) {
    int t2 = e >> 7, c = e & 127;
    pout[(size_t)t2 * CC + c] = part[e];
  }
}

// --------------------------- final reduce over m-tiles ---------------------
__global__ void reduce_kernel(const float* __restrict__ partial,
                              float* __restrict__ out) {
  int idx = blockIdx.x * 256 + threadIdx.x;
  int c    = idx & (CC - 1);
  int comp = (idx >> 10) & (NCOMP - 1);
  int t    = idx >> 15;
  float s = 0.0f;
#pragma unroll
  for (int mt = 0; mt < MTX; ++mt)
    s += partial[(((size_t)(comp * MTX + mt)) * TT + t) * CC + c];
  out[idx] = s * (1.0f / 4096.0f);
}

// ---------------------------------------------------------------------------
extern "C" void kernel_launch(void* const* d_in, const int* in_sizes, int n_in,
                              void* d_out, int out_size, void* d_ws, size_t ws_size,
                              hipStream_t stream) {
  const float* x    = (const float*)d_in[0];
  const int*   ridx = (const int*)d_in[3];
  const float* nW1  = (const float*)d_in[4];
  const float* nb1  = (const float*)d_in[5];
  const float* nW2  = (const float*)d_in[6];
  const float* nb2  = (const float*)d_in[7];
  const float* eW1  = (const float*)d_in[8];
  const float* eb1  = (const float*)d_in[9];
  const float* eW2  = (const float*)d_in[10];
  const float* eb2  = (const float*)d_in[11];
  float* out = (float*)d_out;

  // ws: [h 134MB][bitmap][keep][partial 8.4MB][Ab 134MB]  ~277 MB
  const size_t H_B   = (size_t)NCOMP * MP * HH * 2;
  const size_t BMP_B = (size_t)NCOMP * 1024 * 4;
  const size_t KP_B  = (size_t)NCOMP * 1024 * 4;
  const size_t PRT_B = (size_t)NCOMP * MTX * TT * CC * 4;
  const size_t base  = H_B + BMP_B + KP_B + PRT_B;

  char* ws = (char*)d_ws;
  short* hbuf      = (short*)ws;
  unsigned* bitmap = (unsigned*)(ws + H_B);
  float* keepf     = (float*)(ws + H_B + BMP_B);
  float* partial   = (float*)(ws + H_B + BMP_B + KP_B);
  short* Ab        = (short*)(ws + base);

  hipMemsetAsync(bitmap, 0, BMP_B, stream);
  dedup_kernel<<<NCOMP, 256, 0, stream>>>(ridx, bitmap, keepf);
  gather_kernel<<<NCOMP * 128, 256, 0, stream>>>(x, ridx, Ab);
  gemm1_kernel<<<NCOMP * MTX * NT1, 256, 0, stream>>>(nW1, nb1, eW1, eb1, Ab, hbuf);
  gemm2_kernel<<<NCOMP * MTX * NT2, 256, 0, stream>>>(hbuf, ridx, nW2, nb2, eW2, eb2, keepf, partial);
  reduce_kernel<<<out_size / 256, 256, 0, stream>>>(partial, out);
}